// Round 1
// 968.626 us; speedup vs baseline: 1.0126x; 1.0126x over previous
//
#include <hip/hip_runtime.h>
#include <hip/hip_fp16.h>
#include <math.h>

#define NN 50000
#define EE 800000
#define HIDDEN 128
#define NGRAPH 50
#define GEMM_TILES ((NN + 63) / 64)

typedef _Float16 half8 __attribute__((ext_vector_type(8)));
typedef float f32x4 __attribute__((ext_vector_type(4)));

// ---------------- CSR degree count + weight transpose (union grid) ----------------
__global__ void k_degprep(const int* __restrict__ eidx, int* __restrict__ cnt,
                          const float* __restrict__ Wq, const float* __restrict__ Wk,
                          const float* __restrict__ Wv, const float* __restrict__ Ws,
                          _Float16* __restrict__ wt) {
    int b = blockIdx.x;
    int t = threadIdx.x;
    if (b < 3125) {
        int e = b * 256 + t;
        if (e < EE) atomicAdd(&cnt[eidx[EE + e]], 1);
    } else {
        int idx = (b - 3125) * 256 + t;   // 12 * 16384 fp16 transposed weights
        if (idx < 12 * 16384) {
            int mat = idx >> 14;
            int l = mat >> 2, w = mat & 3;
            int nk = idx & 16383;
            int n = nk >> 7, k = nk & 127;
            const float* W = (w == 0 ? Wq : w == 1 ? Wk : w == 2 ? Wv : Ws) + (size_t)l * 16384;
            wt[idx] = (_Float16)W[k * 128 + n];
        }
    }
}

// scan + housekeeping: exclusive-scan deg->row_ptr (4 elems/thread), zero cnt,
// zero bn_acc3 / gsum / gcnt
__global__ void k_scan(int* __restrict__ cnt, int* __restrict__ row_ptr,
                       float* __restrict__ bn_acc3, float* __restrict__ gsum,
                       int* __restrict__ gcnt) {
    __shared__ int wsum[16];
    __shared__ int carry_s;
    int t = threadIdx.x;
    int lane = t & 63, w = t >> 6;
    if (t < 768) bn_acc3[t] = 0.f;
    if (t < 64) { gsum[t] = 0.f; gcnt[t] = 0; }
    if (t == 0) carry_s = 0;
    __syncthreads();
    for (int base = 0; base < NN; base += 4096) {
        int i0 = base + t * 4;
        int v[4];
#pragma unroll
        for (int j = 0; j < 4; j++) v[j] = (i0 + j < NN) ? cnt[i0 + j] : 0;
        int s4 = v[0] + v[1] + v[2] + v[3];
        int s = s4;
#pragma unroll
        for (int o = 1; o < 64; o <<= 1) {
            int u = __shfl_up(s, o);
            if (lane >= o) s += u;
        }
        if (lane == 63) wsum[w] = s;
        __syncthreads();
        if (w == 0) {
            int ws = (lane < 16) ? wsum[lane] : 0;
#pragma unroll
            for (int o = 1; o < 16; o <<= 1) {
                int u = __shfl_up(ws, o);
                if (lane >= o) ws += u;
            }
            if (lane < 16) wsum[lane] = ws;
        }
        __syncthreads();
        int wpre = (w == 0) ? 0 : wsum[w - 1];
        int run = carry_s + wpre + s - s4;
#pragma unroll
        for (int j = 0; j < 4; j++) {
            if (i0 + j < NN) { row_ptr[i0 + j] = run; cnt[i0 + j] = 0; run += v[j]; }
        }
        __syncthreads();
        if (t == 0) carry_s += wsum[15];
        __syncthreads();
    }
    if (t == 0) row_ptr[NN] = carry_s;
}

// ---- GEMM tile body via f16 MFMA: q,xr fp32 out; k,v packed OCP fp8 e4m3 ----
__device__ __forceinline__ void gemm_tile(
    const float* __restrict__ X, const _Float16* __restrict__ wt,
    const float* __restrict__ bq, const float* __restrict__ bk,
    const float* __restrict__ bv, const float* __restrict__ bs,
    const float* ab_s, int use_ab, _Float16 (*xs)[136],
    float* __restrict__ qo, unsigned int* __restrict__ kvb, float* __restrict__ xro,
    int m0)
{
    int t = threadIdx.x;
    int lane = t & 63, wid = t >> 6;
#pragma unroll
    for (int i = 0; i < 8; ++i) {
        int f = t + 256 * i;          // float4 index within 64x32
        int r = f >> 5, c4 = (f & 31) << 2;
        float4 val = make_float4(0.f, 0.f, 0.f, 0.f);
        if (m0 + r < NN) val = *(const float4*)&X[(size_t)(m0 + r) * 128 + c4];
        if (use_ab) {
            float4 a = *(const float4*)&ab_s[c4];
            float4 bb = *(const float4*)&ab_s[128 + c4];
            float z;
            z = fmaf(val.x, a.x, bb.x); val.x = z > 0.f ? z : expm1f(z);
            z = fmaf(val.y, a.y, bb.y); val.y = z > 0.f ? z : expm1f(z);
            z = fmaf(val.z, a.z, bb.z); val.z = z > 0.f ? z : expm1f(z);
            z = fmaf(val.w, a.w, bb.w); val.w = z > 0.f ? z : expm1f(z);
        }
        _Float16* dst = &xs[r][c4];
        dst[0] = (_Float16)val.x; dst[1] = (_Float16)val.y;
        dst[2] = (_Float16)val.z; dst[3] = (_Float16)val.w;
    }
    __syncthreads();
    int quad = lane >> 4, l15 = lane & 15;
    int mrow = wid * 16;
    half8 afrag[4];
#pragma unroll
    for (int kk = 0; kk < 4; kk++)
        afrag[kk] = *(const half8*)&xs[mrow + l15][kk * 32 + quad * 8];

#pragma unroll
    for (int nt = 0; nt < 8; nt++) {
        int c = nt * 16 + l15;
        f32x4 acc[4];
#pragma unroll
        for (int w = 0; w < 4; w++) acc[w] = (f32x4){0.f, 0.f, 0.f, 0.f};
#pragma unroll
        for (int kk = 0; kk < 4; kk++) {
            half8 bf[4];
#pragma unroll
            for (int w = 0; w < 4; w++)
                bf[w] = *(const half8*)&wt[(size_t)w * 16384 + c * 128 + kk * 32 + quad * 8];
#pragma unroll
            for (int w = 0; w < 4; w++)
                acc[w] = __builtin_amdgcn_mfma_f32_16x16x32_f16(afrag[kk], bf[w], acc[w], 0, 0, 0);
        }
        float bqv = bq[c], bkv = bk[c], bvv = bv[c], bsv = bs[c];
        int nodebase = m0 + mrow + quad * 4;
#pragma unroll
        for (int r = 0; r < 4; r++) {
            int node = nodebase + r;
            bool ok = node < NN;
            float qv = acc[0][r] + bqv;
            float xv = acc[3][r] + bsv;
            float kf = acc[1][r] + bkv;
            float vf = acc[2][r] + bvv;
            float kf1 = __shfl_xor(kf, 1);
            float vf1 = __shfl_xor(vf, 1);
            if (ok) {
                qo[(size_t)node * 128 + c] = qv;
                xro[(size_t)node * 128 + c] = xv;
                if (!(lane & 1)) {
                    int w2 = __builtin_amdgcn_cvt_pk_fp8_f32(kf, kf1, 0, false);
                    w2 = __builtin_amdgcn_cvt_pk_fp8_f32(vf, vf1, w2, true);
                    kvb[(size_t)node * 64 + (c >> 1)] = (unsigned int)w2;
                }
            }
        }
    }
}

// ---- layer-0 GEMM fused with CSR scatter (independent work, union grid) ----
__global__ __launch_bounds__(256) void k_gemm0scat(
    const float* __restrict__ X, const _Float16* __restrict__ wt,
    const float* __restrict__ bq, const float* __restrict__ bk,
    const float* __restrict__ bv, const float* __restrict__ bs,
    float* __restrict__ qo, unsigned int* __restrict__ kvb, float* __restrict__ xro,
    const int* __restrict__ eidx, const float* __restrict__ eattr,
    const int* __restrict__ row_ptr, int* __restrict__ cur,
    int* __restrict__ esrc, float* __restrict__ eat2)
{
    __shared__ _Float16 xs[64][136];
    int b = blockIdx.x;
    if (b < GEMM_TILES) {
        gemm_tile(X, wt, bq, bk, bv, bs, nullptr, 0, xs, qo, kvb, xro, b * 64);
    } else {
        int e = (b - GEMM_TILES) * 256 + threadIdx.x;
        if (e < EE) {
            int d = eidx[EE + e];
            int s = eidx[e];
            int p = atomicAdd(&cur[d], 1);
            int pos = row_ptr[d] + p;
            esrc[pos] = s;
            float2 ea = *(const float2*)&eattr[2 * (size_t)e];
            *(float2*)&eat2[2 * (size_t)pos] = ea;
        }
    }
}

// ---- layers 1,2 GEMM (BN affine+ELU on input from bn_acc stats) ----
__global__ __launch_bounds__(256) void k_gemm4(
    const float* __restrict__ X, const _Float16* __restrict__ wt,
    const float* __restrict__ bq, const float* __restrict__ bk,
    const float* __restrict__ bv, const float* __restrict__ bs,
    const float* __restrict__ bn_acc, const float* __restrict__ gamma,
    const float* __restrict__ beta,
    float* __restrict__ qo, unsigned int* __restrict__ kvb, float* __restrict__ xro)
{
    __shared__ _Float16 xs[64][136];
    __shared__ float ab_s[256];
    int t = threadIdx.x;
    if (t < 128) {
        float mu = bn_acc[t] * (1.f / NN);
        float var = bn_acc[128 + t] * (1.f / NN) - mu * mu;
        float inv = rsqrtf(var + 1e-5f);
        float a = inv * gamma[t];
        ab_s[t] = a;
        ab_s[128 + t] = beta[t] - mu * a;
    }
    __syncthreads();
    gemm_tile(X, wt, bq, bk, bv, bs, ab_s, 1, xs, qo, kvb, xro, blockIdx.x * 64);
}

// 16-lane (per-head) sum via DPP row rotations — VALU-only, no DS-pipe ops.
__device__ __forceinline__ float row_sum16(float p) {
    p += __int_as_float(__builtin_amdgcn_update_dpp(0, __float_as_int(p), 0x128, 0xF, 0xF, true)); // row_ror:8
    p += __int_as_float(__builtin_amdgcn_update_dpp(0, __float_as_int(p), 0x124, 0xF, 0xF, true)); // row_ror:4
    p += __int_as_float(__builtin_amdgcn_update_dpp(0, __float_as_int(p), 0x122, 0xF, 0xF, true)); // row_ror:2
    p += __int_as_float(__builtin_amdgcn_update_dpp(0, __float_as_int(p), 0x121, 0xF, 0xF, true)); // row_ror:1
    return p;
}

// ---------------- attention + gate + BN-stats ----------------
// v2: 4 contiguous nodes per wave, round-robin interleaved groups of 8 edges
// (up to 32 fp8 kv gathers in flight), masked padding instead of serial tail,
// per-edge (src,attr) staged in LDS (uniform ds_read = broadcast) instead of
// ds_bpermute shuffles, head-dot reduce via DPP instead of shfl_xor.
// NN = 50000 = 3125 blocks * 4 waves * 4 nodes exactly.
__global__ __launch_bounds__(256, 4) void k_attn(
    const float* __restrict__ q, const unsigned int* __restrict__ kvb,
    const float* __restrict__ xr,
    const int* __restrict__ esrc, const float* __restrict__ eat2,
    const int* __restrict__ row_ptr,
    const float* __restrict__ We, const float* __restrict__ be,
    const float* __restrict__ Wb,
    float* __restrict__ out2, float* __restrict__ bn_accum)
{
    __shared__ float4 es[4][4][64];   // [wave][node][slot] = {eax, eay, src_bits, pad}
    int t = threadIdx.x;
    int lane = t & 63;
    int wid = t >> 6;
    int gwave = blockIdx.x * 4 + wid;     // 0..12499
    int nb = gwave * 4;                    // first of 4 contiguous nodes
    int ch = lane * 2;
    float2 we0 = *(const float2*)&We[ch];
    float2 we1 = *(const float2*)&We[128 + ch];
    float2 beL = *(const float2*)&be[ch];
    float2 wb_o = *(const float2*)&Wb[ch];
    float2 wb_r = *(const float2*)&Wb[128 + ch];
    float2 wb_d = *(const float2*)&Wb[256 + ch];
    const float scale = 0.17677669529663687f;   // 1/sqrt(32)
    float bnsx = 0.f, bnsy = 0.f, bnqx = 0.f, bnqy = 0.f;

    // wave-uniform row pointers (SGPRs)
    int rp[5];
#pragma unroll
    for (int i = 0; i < 5; i++)
        rp[i] = __builtin_amdgcn_readfirstlane(row_ptr[nb + i]);

    // q rows for all 4 nodes (issued together)
    float2 qv[4];
#pragma unroll
    for (int i = 0; i < 4; i++)
        qv[i] = *(const float2*)&q[(size_t)(nb + i) * 128 + ch];

    // stage first 64 edges of each node into LDS: lane -> slot
#pragma unroll
    for (int i = 0; i < 4; i++) {
        int mi = rp[i] + lane;
        float4 rec = make_float4(0.f, 0.f, 0.f, 0.f);   // src=0: safe dummy
        if (mi < rp[i + 1]) {
            float2 a = *(const float2*)&eat2[2 * (size_t)mi];
            rec.x = a.x; rec.y = a.y;
            rec.z = __int_as_float(esrc[mi]);
        }
        es[wid][i][lane] = rec;
    }

    float den[4], ax[4], ay[4];
    int cend[4], rnd[4], rmax = 0;
#pragma unroll
    for (int i = 0; i < 4; i++) {
        den[i] = 0.f; ax[i] = 0.f; ay[i] = 0.f;
        int d = rp[i + 1] - rp[i];
        cend[i] = d > 64 ? 64 : d;
        rnd[i] = (cend[i] + 7) >> 3;          // groups of 8 (padded, masked)
        if (rnd[i] > rmax) rmax = rnd[i];
    }

    for (int r = 0; r < rmax; ++r) {
        int b0 = r * 8;
        unsigned int kk[4][8];
        // issue phase: up to 32 kv gathers in flight
#pragma unroll
        for (int i = 0; i < 4; i++) {
            if (r < rnd[i]) {                 // wave-uniform
#pragma unroll
                for (int j = 0; j < 8; j++) {
                    int s = __float_as_int(es[wid][i][b0 + j].z);   // broadcast read
                    kk[i][j] = kvb[(size_t)s * 64 + lane];
                }
            }
        }
        // compute phase
#pragma unroll
        for (int i = 0; i < 4; i++) {
            if (r < rnd[i]) {
#pragma unroll
                for (int j = 0; j < 8; j++) {
                    float2 a = *(const float2*)&es[wid][i][b0 + j]; // eax, eay
                    auto kf = __builtin_amdgcn_cvt_pk_f32_fp8((int)kk[i][j], false);
                    auto vf = __builtin_amdgcn_cvt_pk_f32_fp8((int)kk[i][j], true);
                    float ex_ = fmaf(a.x, we0.x, fmaf(a.y, we1.x, beL.x));
                    float ey_ = fmaf(a.x, we0.y, fmaf(a.y, we1.y, beL.y));
                    float p = qv[i].x * (kf[0] + ex_) + qv[i].y * (kf[1] + ey_);
                    p = row_sum16(p);
                    float exv = (b0 + j < cend[i]) ? __expf(p * scale) : 0.f;
                    den[i] += exv;
                    ax[i] = fmaf(exv, vf[0] + ex_, ax[i]);
                    ay[i] = fmaf(exv, vf[1] + ey_, ay[i]);
                }
            }
        }
    }

    // degree > 64 fallback (astronomically rare for Poisson(16); kept for correctness)
#pragma unroll
    for (int i = 0; i < 4; i++) {
        if (rp[i + 1] - rp[i] > 64) {
            for (int m = rp[i] + 64; m < rp[i + 1]; ++m) {
                int s0 = esrc[m];                                  // uniform address
                float2 a = *(const float2*)&eat2[2 * (size_t)m];
                unsigned int w8 = kvb[(size_t)s0 * 64 + lane];
                auto kf = __builtin_amdgcn_cvt_pk_f32_fp8((int)w8, false);
                auto vf = __builtin_amdgcn_cvt_pk_f32_fp8((int)w8, true);
                float ex_ = fmaf(a.x, we0.x, fmaf(a.y, we1.x, beL.x));
                float ey_ = fmaf(a.x, we0.y, fmaf(a.y, we1.y, beL.y));
                float p = qv[i].x * (kf[0] + ex_) + qv[i].y * (kf[1] + ey_);
                p = row_sum16(p);
                float exv = __expf(p * scale);
                den[i] += exv;
                ax[i] = fmaf(exv, vf[0] + ex_, ax[i]);
                ay[i] = fmaf(exv, vf[1] + ey_, ay[i]);
            }
        }
    }

    // finish: beta gate + store + BN partials (xr loads issued together)
    float2 xv[4];
#pragma unroll
    for (int i = 0; i < 4; i++)
        xv[i] = *(const float2*)&xr[(size_t)(nb + i) * 128 + ch];
#pragma unroll
    for (int i = 0; i < 4; i++) {
        float rden = 1.f / (den[i] + 1e-16f);
        float axs = ax[i] * rden, ays = ay[i] * rden;
        float gp = axs * wb_o.x + ays * wb_o.y + xv[i].x * wb_r.x + xv[i].y * wb_r.y
                 + (axs - xv[i].x) * wb_d.x + (ays - xv[i].y) * wb_d.y;
        gp = row_sum16(gp);
        gp += __shfl_xor(gp, 16);
        gp += __shfl_xor(gp, 32);
        float gate = 1.f / (1.f + __expf(-gp));
        float ox = gate * xv[i].x + (1.f - gate) * axs;
        float oy = gate * xv[i].y + (1.f - gate) * ays;
        *(float2*)&out2[(size_t)(nb + i) * 128 + ch] = make_float2(ox, oy);
        bnsx += ox; bnsy += oy;
        bnqx = fmaf(ox, ox, bnqx); bnqy = fmaf(oy, oy, bnqy);
    }

    // block-level BN partial reduce
    __shared__ float s_sum[2][256], s_sq[2][256];
    s_sum[0][t] = bnsx; s_sum[1][t] = bnsy;
    s_sq[0][t] = bnqx;  s_sq[1][t] = bnqy;
    __syncthreads();
    if (t < 64) {
        float sx = s_sum[0][t] + s_sum[0][64 + t] + s_sum[0][128 + t] + s_sum[0][192 + t];
        float sy = s_sum[1][t] + s_sum[1][64 + t] + s_sum[1][128 + t] + s_sum[1][192 + t];
        float qx = s_sq[0][t] + s_sq[0][64 + t] + s_sq[0][128 + t] + s_sq[0][192 + t];
        float qy = s_sq[1][t] + s_sq[1][64 + t] + s_sq[1][128 + t] + s_sq[1][192 + t];
        int c = 2 * t;
        atomicAdd(&bn_accum[c], sx);
        atomicAdd(&bn_accum[c + 1], sy);
        atomicAdd(&bn_accum[128 + c], qx);
        atomicAdd(&bn_accum[128 + c + 1], qy);
    }
}

// ------- readout: BN affine+ELU+dot(Wout), 4 prefetched loads/wave, LDS per-graph
//         accumulate, one flush per block -------
__global__ __launch_bounds__(256) void k_pool(const float* __restrict__ x,
                                              const float* __restrict__ bn_acc,
                                              const float* __restrict__ gamma,
                                              const float* __restrict__ beta,
                                              const float* __restrict__ Wout,
                                              const int* __restrict__ batch,
                                              float* __restrict__ gsum, int* __restrict__ gcnt) {
    __shared__ float lsum[NGRAPH];
    __shared__ int lcnt[NGRAPH];
    __shared__ float ab_s[256];
    int t = threadIdx.x;
    if (t < NGRAPH) { lsum[t] = 0.f; lcnt[t] = 0; }
    if (t < 128) {
        float mu = bn_acc[t] * (1.f / NN);
        float var = bn_acc[128 + t] * (1.f / NN) - mu * mu;
        float inv = rsqrtf(var + 1e-5f);
        float a = inv * gamma[t];
        ab_s[t] = a;
        ab_s[128 + t] = beta[t] - mu * a;
    }
    __syncthreads();
    int lane = t & 63;
    int wid = t >> 6;
    int ch = lane * 2;
    float2 wo = *(const float2*)&Wout[ch];
    float2 a = *(const float2*)&ab_s[ch];
    float2 b = *(const float2*)&ab_s[128 + ch];
    int base = blockIdx.x * 16 + wid * 4;
    float2 xv[4];
#pragma unroll
    for (int i = 0; i < 4; i++) {          // issue all 4 loads before any use
        int n = base + i;
        xv[i] = (n < NN) ? *(const float2*)&x[(size_t)n * 128 + ch]
                         : make_float2(0.f, 0.f);
    }
#pragma unroll
    for (int i = 0; i < 4; i++) {
        int n = base + i;
        if (n < NN) {
            float z0 = fmaf(xv[i].x, a.x, b.x); z0 = z0 > 0.f ? z0 : expm1f(z0);
            float z1 = fmaf(xv[i].y, a.y, b.y); z1 = z1 > 0.f ? z1 : expm1f(z1);
            float p = z0 * wo.x + z1 * wo.y;
            p += __shfl_xor(p, 1);
            p += __shfl_xor(p, 2);
            p += __shfl_xor(p, 4);
            p += __shfl_xor(p, 8);
            p += __shfl_xor(p, 16);
            p += __shfl_xor(p, 32);
            if (lane == 0) {
                int g = batch[n];
                atomicAdd(&lsum[g], p);
                atomicAdd(&lcnt[g], 1);
            }
        }
    }
    __syncthreads();
    if (t < NGRAPH && lcnt[t] > 0) {
        atomicAdd(&gsum[t], lsum[t]);
        atomicAdd(&gcnt[t], lcnt[t]);
    }
}

__global__ void k_final(const float* __restrict__ gsum, const int* __restrict__ gcnt,
                        const float* __restrict__ bout, const float* __restrict__ obias,
                        float* __restrict__ out) {
    int g = threadIdx.x;
    if (g < NGRAPH) out[g] = gsum[g] / fmaxf((float)gcnt[g], 1.f) + bout[0] + obias[0];
}

extern "C" void kernel_launch(void* const* d_in, const int* in_sizes, int n_in,
                              void* d_out, int out_size, void* d_ws, size_t ws_size,
                              hipStream_t stream) {
    const float* x_in       = (const float*)d_in[0];
    const int* eidx         = (const int*)d_in[1];
    const float* eattr      = (const float*)d_in[2];
    const int* batch        = (const int*)d_in[3];
    const float* Wq         = (const float*)d_in[4];
    const float* bq         = (const float*)d_in[5];
    const float* Wk         = (const float*)d_in[6];
    const float* bk         = (const float*)d_in[7];
    const float* Wv         = (const float*)d_in[8];
    const float* bv         = (const float*)d_in[9];
    const float* We         = (const float*)d_in[10];
    const float* be         = (const float*)d_in[11];
    const float* Wskip      = (const float*)d_in[12];
    const float* bskip      = (const float*)d_in[13];
    const float* Wbeta      = (const float*)d_in[14];
    const float* bn_gamma   = (const float*)d_in[15];
    const float* bn_beta    = (const float*)d_in[16];
    const float* Wout       = (const float*)d_in[17];
    const float* bout       = (const float*)d_in[18];
    const float* obias      = (const float*)d_in[19];
    float* out = (float*)d_out;

    char* ws = (char*)d_ws;
    size_t off = 0;
    auto alloc = [&](size_t bytes) -> void* {
        off = (off + 255) & ~(size_t)255;
        void* p = ws + off;
        off += bytes;
        return p;
    };
    const size_t NF = (size_t)NN * 128 * sizeof(float);
    float* xbuf    = (float*)alloc(NF);
    float* qb      = (float*)alloc(NF);
    float* xrb     = (float*)alloc(NF);
    unsigned int* kvb = (unsigned int*)alloc((size_t)NN * 64 * sizeof(unsigned int));
    _Float16* wt   = (_Float16*)alloc((size_t)12 * 16384 * sizeof(_Float16));
    int* row_ptr   = (int*)alloc((NN + 1) * sizeof(int));
    int* cnt       = (int*)alloc(NN * sizeof(int));
    int* esrc      = (int*)alloc(EE * sizeof(int));
    float* eat2    = (float*)alloc((size_t)EE * 2 * sizeof(float));
    float* bn_acc3 = (float*)alloc(3 * 256 * sizeof(float));
    float* gsum    = (float*)alloc(64 * sizeof(float));
    int* gcnt      = (int*)alloc(64 * sizeof(int));
    (void)ws_size; (void)n_in; (void)in_sizes; (void)out_size;

    // ---- CSR degree + weight prep, scan (also zeroes aux) ----
    hipMemsetAsync(cnt, 0, NN * sizeof(int), stream);
    k_degprep<<<3125 + 768, 256, 0, stream>>>(eidx, cnt, Wq, Wk, Wv, Wskip, wt);
    k_scan<<<1, 1024, 0, stream>>>(cnt, row_ptr, bn_acc3, gsum, gcnt);

    // ---- layer 0 GEMM + CSR scatter fused (independent work) ----
    k_gemm0scat<<<GEMM_TILES + 3125, 256, 0, stream>>>(
        x_in, wt, bq, bk, bv, bskip, qb, kvb, xrb,
        eidx, eattr, row_ptr, cnt, esrc, eat2);
    k_attn<<<3125, 256, 0, stream>>>(
        qb, kvb, xrb, esrc, eat2, row_ptr,
        We, be, Wbeta, xbuf, bn_acc3);

    // ---- layers 1,2 ----
    for (int l = 1; l < 3; ++l) {
        k_gemm4<<<GEMM_TILES, 256, 0, stream>>>(
            xbuf, wt + (size_t)l * 65536,
            bq + l * 128, bk + l * 128, bv + l * 128, bskip + l * 128,
            bn_acc3 + (l - 1) * 256, bn_gamma + (l - 1) * 128, bn_beta + (l - 1) * 128,
            qb, kvb, xrb);
        k_attn<<<3125, 256, 0, stream>>>(
            qb, kvb, xrb, esrc, eat2, row_ptr,
            We + (size_t)l * 256, be + l * 128, Wbeta + (size_t)l * 384,
            xbuf, bn_acc3 + l * 256);
    }

    // ---- readout (BN affine+ELU of layer-2 fused in) ----
    k_pool<<<(NN + 15) / 16, 256, 0, stream>>>(xbuf, bn_acc3 + 2 * 256,
                                               bn_gamma + 2 * 128, bn_beta + 2 * 128,
                                               Wout, batch, gsum, gcnt);
    k_final<<<1, 64, 0, stream>>>(gsum, gcnt, bout, obias, out);
}